// Round 7
// baseline (120.870 us; speedup 1.0000x reference)
//
#include <hip/hip_runtime.h>
#include <stdint.h>

// Swin shifted-window attention, MI355X (gfx950) — MFMA version, round 7.
// Round-6 body, but 1024-thread blocks (16 waves/WG, all 16 heads of one
// window). Theory: residency was capped at ~3 workgroups/CU (38% occupancy
// with only 60 VGPRs) -> pack 16 waves per WG slot so 2 WGs/CU = 100%.
// One wave per (window, head); no LDS, no barriers.

constexpr int WSZ  = 7;
constexpr int NTOK = 49;
constexpr int NH_  = 16;
constexpr int HD_  = 32;
constexpr int SP   = 56;
constexpr int CH   = 512;
constexpr float LOG2E = 1.4426950408889634f;

typedef float  f32x4 __attribute__((ext_vector_type(4)));
typedef short  s16x8 __attribute__((ext_vector_type(8)));

union FragU { uint32_t w[4]; s16x8 v; };

// round-to-nearest-even bf16 of a float, as the TOP 16 bits (low 16 zero)
__device__ inline uint32_t bf16_hibits(float x) {
    uint32_t u = __float_as_uint(x);
    u += 0x7fffu + ((u >> 16) & 1u);
    return u & 0xffff0000u;
}

// pack two floats to bf16 pair (low half = a, high half = b)
__device__ inline uint32_t pk_bf16(float a, float b) {
    return (bf16_hibits(a) >> 16) | bf16_hibits(b);
}

// hi/lo bf16 split of a pair: wh = bf16(a,b); wl = bf16 of residuals
__device__ inline void hilo_pair(float a, float b, uint32_t& wh, uint32_t& wl) {
    uint32_t ah = bf16_hibits(a), bh = bf16_hibits(b);
    wh = (ah >> 16) | bh;
    float ra = a - __uint_as_float(ah);
    float rb = b - __uint_as_float(bh);
    wl = pk_bf16(ra, rb);
}

// ---------------- pre-kernel: bias+mask matrices ----------------
// bm[h][cls][q][m] (64x64 each), cls = (wr==7)*2 + (wc==7).
// value = LOG2E*(bias + mask) - 23 for valid q,m<49; -1e9 for padding.
__global__ __launch_bounds__(256)
void build_bm(const float* __restrict__ bias, float* __restrict__ bm)
{
    const int blk = blockIdx.x;          // h*4 + cls
    const int h = blk >> 2, cls = blk & 3;
    for (int idx = threadIdx.x; idx < 4096; idx += 256) {
        const int q = idx >> 6, m = idx & 63;
        float val;
        if (q >= NTOK || m >= NTOK) {
            val = -1e9f;
        } else {
            const int iq = q / 7, jq = q % 7, im = m / 7, jm = m % 7;
            const int rpi = (iq - im + 6) * 13 + (jq - jm + 6);
            const float bv = bias[rpi * NH_ + h];
            const int rq = ((cls & 2) ? (iq < 4 ? 3 : 6) : 0)
                         + ((cls & 1) ? (jq < 4 ? 1 : 2) : 0);
            const int rm = ((cls & 2) ? (im < 4 ? 3 : 6) : 0)
                         + ((cls & 1) ? (jm < 4 ? 1 : 2) : 0);
            const float mask = (rq != rm) ? -100.0f : 0.0f;
            val = (bv + mask) * LOG2E - 23.0f;
        }
        bm[blk * 4096 + idx] = val;
    }
}

// ---------------- main MFMA kernel ----------------
__global__ __launch_bounds__(1024, 4)
void swin_mfma_kernel(const float* __restrict__ qg,
                      const float* __restrict__ kg,
                      const float* __restrict__ vg,
                      const float* __restrict__ bm,
                      float* __restrict__ outg)
{
    const int wave = threadIdx.x >> 6;        // 0..15 = head
    const int wh   = blockIdx.x * 16 + wave;  // window-head id
    const int h    = wh & (NH_ - 1);
    const int w    = wh >> 4;                 // = blockIdx.x (window id)
    const int wc   = w & 7;
    const int wr   = (w >> 3) & 7;
    const int b    = w >> 6;

    const int lane = threadIdx.x & 63;
    const int g    = lane >> 4;       // 16-lane group 0..3
    const int l16  = lane & 15;

    // per-lane token offset: token = lane (clamped to 48)
    const int t  = lane < NTOK ? lane : NTOK - 1;
    const int it = t / 7, jt = t - 7 * it;
    int sr = wr * 7 + it + 3; if (sr >= SP) sr -= SP;
    int sc = wc * 7 + jt + 3; if (sc >= SP) sc -= SP;
    const int off_t = ((b * SP + sr) * SP + sc) * CH + h * HD_;

    const float qs = 0.17677669529663687f * LOG2E;  // (1/sqrt(32))*log2(e)

    // ---- load Q,K (token = 16*tt + l16, d = 8g..8g+7), convert per tile ----
    // Q: single bf16 (pre-scaled). K: hi/lo split (keeps 1st-order K residual).
    s16x8 Qh[4], Kh[4], Kl[4];
#pragma unroll
    for (int tt = 0; tt < 4; ++tt) {
        const int o = __shfl(off_t, 16 * tt + l16);
        const float* qp = qg + o + 8 * g;
        const float* kp = kg + o + 8 * g;
        float4 q0 = *(const float4*)qp;
        float4 q1 = *(const float4*)(qp + 4);
        float4 k0 = *(const float4*)kp;
        float4 k1 = *(const float4*)(kp + 4);
        FragU qh, kh, kl;
        qh.w[0] = pk_bf16(q0.x * qs, q0.y * qs);
        qh.w[1] = pk_bf16(q0.z * qs, q0.w * qs);
        qh.w[2] = pk_bf16(q1.x * qs, q1.y * qs);
        qh.w[3] = pk_bf16(q1.z * qs, q1.w * qs);
        hilo_pair(k0.x, k0.y, kh.w[0], kl.w[0]);
        hilo_pair(k0.z, k0.w, kh.w[1], kl.w[1]);
        hilo_pair(k1.x, k1.y, kh.w[2], kl.w[2]);
        hilo_pair(k1.z, k1.w, kh.w[3], kl.w[3]);
        Qh[tt] = qh.v; Kh[tt] = kh.v; Kl[tt] = kl.v;
    }

    // ---- load V (token m = 32mc + 8g + e, d = 16dh + l16), single bf16 ----
    s16x8 Vb[2][2];
#pragma unroll
    for (int mc = 0; mc < 2; ++mc) {
        int vo[8];
#pragma unroll
        for (int e = 0; e < 8; ++e)
            vo[e] = __shfl(off_t, 32 * mc + 8 * g + e);
#pragma unroll
        for (int dh = 0; dh < 2; ++dh) {
            FragU fu;
#pragma unroll
            for (int wd = 0; wd < 4; ++wd) {
                float a = vg[vo[2 * wd]     + 16 * dh + l16];
                float c = vg[vo[2 * wd + 1] + 16 * dh + l16];
                fu.w[wd] = pk_bf16(a, c);
            }
            Vb[mc][dh] = fu.v;
        }
    }

    // ---- S^T = K·Q^T tile loop, fused exp2 + bf16 pack + denom ----
    const int cls = ((wr == 7) ? 2 : 0) | ((wc == 7) ? 1 : 0);
    const float* bmh = bm + (h * 4 + cls) * 4096;

    uint32_t u0[4][4], u1[4][4];
    float inv[4];
#pragma unroll
    for (int tq = 0; tq < 4; ++tq) {
        float dsum = 0.f;
#pragma unroll
        for (int tk = 0; tk < 4; ++tk) {
            f32x4 a = *(const f32x4*)(bmh + (16 * tq + l16) * 64 + 16 * tk + 4 * g);
            a = __builtin_amdgcn_mfma_f32_16x16x32_bf16(Kl[tk], Qh[tq], a, 0, 0, 0);
            a = __builtin_amdgcn_mfma_f32_16x16x32_bf16(Kh[tk], Qh[tq], a, 0, 0, 0);
            float e0 = __builtin_amdgcn_exp2f(a[0]);
            float e1 = __builtin_amdgcn_exp2f(a[1]);
            float e2 = __builtin_amdgcn_exp2f(a[2]);
            float e3 = __builtin_amdgcn_exp2f(a[3]);
            dsum += (e0 + e1) + (e2 + e3);
            u0[tq][tk] = pk_bf16(e0, e1);
            u1[tq][tk] = pk_bf16(e2, e3);
        }
        dsum += __shfl_xor(dsum, 16);
        dsum += __shfl_xor(dsum, 32);
        inv[tq] = 1.0f / (dsum + 1e-30f);
    }

    // ---- repack P (C-layout) -> A-fragments for PV ----
    // dest A-frag PA[tq][mc]: lane holds P[q=16tq+l16][m=32mc+8g+e]
    // word w (e=2w,2w+1): src lane = 32*(g&1) + 16*(w>>1) + l16,
    // src tile tk = 2mc + (g>>1) (select via lane>=32), src word = u_{w&1}
    const int srcb = 32 * (g & 1) + l16;
    const bool hiG = (lane >= 32);
    s16x8 PA[4][2];
#pragma unroll
    for (int tq = 0; tq < 4; ++tq)
#pragma unroll
        for (int mc = 0; mc < 2; ++mc) {
            FragU fu;
#pragma unroll
            for (int wd = 0; wd < 4; ++wd) {
                const int sl = srcb + 16 * (wd >> 1);
                uint32_t A, B;
                if (wd & 1) {
                    A = __shfl(u1[tq][2 * mc],     sl);
                    B = __shfl(u1[tq][2 * mc + 1], sl);
                } else {
                    A = __shfl(u0[tq][2 * mc],     sl);
                    B = __shfl(u0[tq][2 * mc + 1], sl);
                }
                fu.w[wd] = hiG ? B : A;
            }
            PA[tq][mc] = fu.v;
        }

    // ---- O = P·V, normalize + store ----
    // row q = 16tq + 4g + r, col d = 16dh + l16
#pragma unroll
    for (int tq = 0; tq < 4; ++tq) {
        f32x4 acc[2];
#pragma unroll
        for (int dh = 0; dh < 2; ++dh) {
            f32x4 a = {0.f, 0.f, 0.f, 0.f};
            a = __builtin_amdgcn_mfma_f32_16x16x32_bf16(PA[tq][0], Vb[0][dh], a, 0, 0, 0);
            a = __builtin_amdgcn_mfma_f32_16x16x32_bf16(PA[tq][1], Vb[1][dh], a, 0, 0, 0);
            acc[dh] = a;
        }
#pragma unroll
        for (int r = 0; r < 4; ++r) {
            const float iv = __shfl(inv[tq], 4 * g + r);
            const int oo = __shfl(off_t, 16 * tq + 4 * g + r);
            if (tq < 3 || (g == 0 && r == 0)) {
#pragma unroll
                for (int dh = 0; dh < 2; ++dh)
                    outg[oo + 16 * dh + l16] = acc[dh][r] * iv;
            }
        }
    }
}

// ---------------- fallback scalar kernel (round-3) ----------------
__global__ __launch_bounds__(256)
void swin_block_scalar(const float* __restrict__ qg,
                       const float* __restrict__ kg,
                       const float* __restrict__ vg,
                       const float* __restrict__ bias,
                       float* __restrict__ outg)
{
    const int wave = __builtin_amdgcn_readfirstlane(threadIdx.x >> 6);
    const int wh   = blockIdx.x * 4 + wave;
    const int h    = wh & (NH_ - 1);
    const int w    = wh >> 4;
    const int wc   = w & 7;
    const int wr   = (w >> 3) & 7;
    const int b    = w >> 6;

    const int lane = threadIdx.x & 63;
    const int rr   = lane < NTOK ? lane : NTOK - 1;
    const int i    = rr / WSZ;
    const int j    = rr - i * WSZ;

    const int hp = wr * WSZ + i;
    const int wp = wc * WSZ + j;
    int sr = hp + 3; if (sr >= SP) sr -= SP;
    int sc = wp + 3; if (sc >= SP) sc -= SP;
    const int rowoff = ((b * SP + sr) * SP + sc) * CH + h * HD_;
    const int reg_r = (hp < 49 ? 0 : (hp < 53 ? 3 : 6))
                    + (wp < 49 ? 0 : (wp < 53 ? 1 : 2));
    const float qscale = 0.17677669529663687f * LOG2E;

    float qr[HD_];
    {
        const float4* qp = reinterpret_cast<const float4*>(qg + rowoff);
#pragma unroll
        for (int tt = 0; tt < HD_ / 4; ++tt) {
            float4 x = qp[tt];
            qr[4*tt+0] = x.x * qscale; qr[4*tt+1] = x.y * qscale;
            qr[4*tt+2] = x.z * qscale; qr[4*tt+3] = x.w * qscale;
        }
    }
    const int biaslane = (i * 13 + j) * 16 + h;
    float o[HD_];
#pragma unroll
    for (int d = 0; d < HD_; ++d) o[d] = 0.f;
    float denom = 0.f;
    const float* kb = kg + b * SP * SP * CH + h * HD_;
    const float* vb = vg + b * SP * SP * CH + h * HD_;

    for (int ic = 0; ic < WSZ; ++ic) {
        const int hpc = wr * WSZ + ic;
        int src_r = hpc + 3; if (src_r >= SP) src_r -= SP;
        const int regh_c = (hpc < 49 ? 0 : (hpc < 53 ? 3 : 6));
        const float* krow0 = kb + src_r * SP * CH;
        const float* vrow0 = vb + src_r * SP * CH;
        float e[WSZ];
#pragma unroll
        for (int u = 0; u < WSZ; ++u) {
            const int wpc = wc * WSZ + u;
            int src_c = wpc + 3; if (src_c >= SP) src_c -= SP;
            const int reg_c = regh_c + (wpc < 49 ? 0 : (wpc < 53 ? 1 : 2));
            const float* krow = krow0 + src_c * CH;
            const float bv = bias[biaslane + ((6 - ic) * 13 + (6 - u)) * 16];
            float s0 = fmaf(bv, LOG2E, (reg_r != reg_c) ? -167.26950408889634f : -23.0f);
            float s1 = 0.f, s2 = 0.f, s3 = 0.f;
#pragma unroll
            for (int d = 0; d < HD_; d += 4) {
                s0 = fmaf(qr[d+0], krow[d+0], s0);
                s1 = fmaf(qr[d+1], krow[d+1], s1);
                s2 = fmaf(qr[d+2], krow[d+2], s2);
                s3 = fmaf(qr[d+3], krow[d+3], s3);
            }
            e[u] = exp2f((s0 + s1) + (s2 + s3));
            denom += e[u];
        }
#pragma unroll
        for (int u = 0; u < WSZ; ++u) {
            const int wpc = wc * WSZ + u;
            int src_c = wpc + 3; if (src_c >= SP) src_c -= SP;
            const float* vrow = vrow0 + src_c * CH;
            const float ev = e[u];
#pragma unroll
            for (int d = 0; d < HD_; ++d) o[d] = fmaf(ev, vrow[d], o[d]);
        }
    }
    const float invd = 1.0f / denom;
    if (lane < NTOK) {
        float4* op = reinterpret_cast<float4*>(outg + rowoff);
#pragma unroll
        for (int tt = 0; tt < HD_ / 4; ++tt) {
            float4 x;
            x.x = o[4*tt+0] * invd; x.y = o[4*tt+1] * invd;
            x.z = o[4*tt+2] * invd; x.w = o[4*tt+3] * invd;
            op[tt] = x;
        }
    }
}

extern "C" void kernel_launch(void* const* d_in, const int* in_sizes, int n_in,
                              void* d_out, int out_size, void* d_ws, size_t ws_size,
                              hipStream_t stream) {
    const float* q    = (const float*)d_in[0];
    const float* k    = (const float*)d_in[1];
    const float* v    = (const float*)d_in[2];
    const float* bias = (const float*)d_in[3];
    float* out        = (float*)d_out;

    const int B   = in_sizes[0] / (SP * SP * CH);
    const int nwh = B * (SP / WSZ) * (SP / WSZ) * NH_;   // 16384

    const size_t bm_bytes = (size_t)NH_ * 4 * 64 * 64 * sizeof(float);  // 1 MB
    if (ws_size >= bm_bytes) {
        float* bm = (float*)d_ws;
        hipLaunchKernelGGL(build_bm, dim3(NH_ * 4), dim3(256), 0, stream, bias, bm);
        hipLaunchKernelGGL(swin_mfma_kernel, dim3(nwh / 16), dim3(1024), 0, stream,
                           q, k, v, bm, out);
    } else {
        hipLaunchKernelGGL(swin_block_scalar, dim3(nwh / 4), dim3(256), 0, stream,
                           q, k, v, bias, out);
    }
}

// Round 8
// 118.425 us; speedup vs baseline: 1.0206x; 1.0206x over previous
//
#include <hip/hip_runtime.h>
#include <stdint.h>

// Swin shifted-window attention, MI355X (gfx950) — MFMA version, round 8.
// Key change vs r6/r7: per-wave MEMORY-LEVEL PARALLELISM. Per-wave time was
// ~60k cycles ≈ 64 loads x ~900cy serialized: the 128-reg budget forced the
// compiler to roll loads into load->convert->reuse chains. Now: all 20
// addresses first, then ALL 64 Q/K/V loads issued back-to-back into distinct
// registers, then convert. __launch_bounds__(256,2) = 256-reg budget; fewer
// resident waves but each has its full load set in flight (HBM-latency ->
// HBM-bandwidth regime). One wave per (window,head); no LDS, no barriers.

constexpr int WSZ  = 7;
constexpr int NTOK = 49;
constexpr int NH_  = 16;
constexpr int HD_  = 32;
constexpr int SP   = 56;
constexpr int CH   = 512;
constexpr float LOG2E = 1.4426950408889634f;

typedef float  f32x4 __attribute__((ext_vector_type(4)));
typedef short  s16x8 __attribute__((ext_vector_type(8)));

union FragU { uint32_t w[4]; s16x8 v; };

// round-to-nearest-even bf16 of a float, as the TOP 16 bits (low 16 zero)
__device__ inline uint32_t bf16_hibits(float x) {
    uint32_t u = __float_as_uint(x);
    u += 0x7fffu + ((u >> 16) & 1u);
    return u & 0xffff0000u;
}

// pack two floats to bf16 pair (low half = a, high half = b)
__device__ inline uint32_t pk_bf16(float a, float b) {
    return (bf16_hibits(a) >> 16) | bf16_hibits(b);
}

// hi/lo bf16 split of a pair: wh = bf16(a,b); wl = bf16 of residuals
__device__ inline void hilo_pair(float a, float b, uint32_t& wh, uint32_t& wl) {
    uint32_t ah = bf16_hibits(a), bh = bf16_hibits(b);
    wh = (ah >> 16) | bh;
    float ra = a - __uint_as_float(ah);
    float rb = b - __uint_as_float(bh);
    wl = pk_bf16(ra, rb);
}

// ---------------- pre-kernel: bias+mask matrices ----------------
// bm[h][cls][q][m] (64x64 each), cls = (wr==7)*2 + (wc==7).
// value = LOG2E*(bias + mask) - 23 for valid q,m<49; -1e9 for padding.
__global__ __launch_bounds__(256)
void build_bm(const float* __restrict__ bias, float* __restrict__ bm)
{
    const int blk = blockIdx.x;          // h*4 + cls
    const int h = blk >> 2, cls = blk & 3;
    for (int idx = threadIdx.x; idx < 4096; idx += 256) {
        const int q = idx >> 6, m = idx & 63;
        float val;
        if (q >= NTOK || m >= NTOK) {
            val = -1e9f;
        } else {
            const int iq = q / 7, jq = q % 7, im = m / 7, jm = m % 7;
            const int rpi = (iq - im + 6) * 13 + (jq - jm + 6);
            const float bv = bias[rpi * NH_ + h];
            const int rq = ((cls & 2) ? (iq < 4 ? 3 : 6) : 0)
                         + ((cls & 1) ? (jq < 4 ? 1 : 2) : 0);
            const int rm = ((cls & 2) ? (im < 4 ? 3 : 6) : 0)
                         + ((cls & 1) ? (jm < 4 ? 1 : 2) : 0);
            const float mask = (rq != rm) ? -100.0f : 0.0f;
            val = (bv + mask) * LOG2E - 23.0f;
        }
        bm[blk * 4096 + idx] = val;
    }
}

// ---------------- main MFMA kernel ----------------
__global__ __launch_bounds__(256, 2)
void swin_mfma_kernel(const float* __restrict__ qg,
                      const float* __restrict__ kg,
                      const float* __restrict__ vg,
                      const float* __restrict__ bm,
                      float* __restrict__ outg)
{
    const int wave = threadIdx.x >> 6;
    const int wh   = blockIdx.x * 4 + wave;
    const int h    = wh & (NH_ - 1);
    const int w    = wh >> 4;
    const int wc   = w & 7;
    const int wr   = (w >> 3) & 7;
    const int b    = w >> 6;

    const int lane = threadIdx.x & 63;
    const int g    = lane >> 4;       // 16-lane group 0..3
    const int l16  = lane & 15;

    // per-lane token offset: token = lane (clamped to 48)
    const int t  = lane < NTOK ? lane : NTOK - 1;
    const int it = t / 7, jt = t - 7 * it;
    int sr = wr * 7 + it + 3; if (sr >= SP) sr -= SP;
    int sc = wc * 7 + jt + 3; if (sc >= SP) sc -= SP;
    const int off_t = ((b * SP + sr) * SP + sc) * CH + h * HD_;

    // ---- phase 1: ALL addresses (shuffles), then ALL raw loads ----
    int oQK[4];
#pragma unroll
    for (int tt = 0; tt < 4; ++tt)
        oQK[tt] = __shfl(off_t, 16 * tt + l16);
    int oV[16];
#pragma unroll
    for (int mc = 0; mc < 2; ++mc)
#pragma unroll
        for (int e = 0; e < 8; ++e)
            oV[8 * mc + e] = __shfl(off_t, 32 * mc + 8 * g + e);

    // Q,K: token = 16*tt + l16, d = 8g..8g+7  (16 x float4, independent)
    float4 qa[4][2], ka[4][2];
#pragma unroll
    for (int tt = 0; tt < 4; ++tt) {
        const float* qp = qg + oQK[tt] + 8 * g;
        const float* kp = kg + oQK[tt] + 8 * g;
        qa[tt][0] = *(const float4*)qp;
        qa[tt][1] = *(const float4*)(qp + 4);
        ka[tt][0] = *(const float4*)kp;
        ka[tt][1] = *(const float4*)(kp + 4);
    }
    // V: token m = 32mc + 8g + e, d = 16dh + l16  (32 scalar, independent)
    float va[2][2][8];
#pragma unroll
    for (int mc = 0; mc < 2; ++mc)
#pragma unroll
        for (int dh = 0; dh < 2; ++dh)
#pragma unroll
            for (int e = 0; e < 8; ++e)
                va[mc][dh][e] = vg[oV[8 * mc + e] + 16 * dh + l16];

    const float qs = 0.17677669529663687f * LOG2E;  // (1/sqrt(32))*log2(e)

    // ---- phase 2: converts ----
    // Q: single bf16 (pre-scaled). K: hi/lo split. V: single bf16.
    s16x8 Qh[4], Kh[4], Kl[4];
#pragma unroll
    for (int tt = 0; tt < 4; ++tt) {
        FragU qh, kh, kl;
        qh.w[0] = pk_bf16(qa[tt][0].x * qs, qa[tt][0].y * qs);
        qh.w[1] = pk_bf16(qa[tt][0].z * qs, qa[tt][0].w * qs);
        qh.w[2] = pk_bf16(qa[tt][1].x * qs, qa[tt][1].y * qs);
        qh.w[3] = pk_bf16(qa[tt][1].z * qs, qa[tt][1].w * qs);
        hilo_pair(ka[tt][0].x, ka[tt][0].y, kh.w[0], kl.w[0]);
        hilo_pair(ka[tt][0].z, ka[tt][0].w, kh.w[1], kl.w[1]);
        hilo_pair(ka[tt][1].x, ka[tt][1].y, kh.w[2], kl.w[2]);
        hilo_pair(ka[tt][1].z, ka[tt][1].w, kh.w[3], kl.w[3]);
        Qh[tt] = qh.v; Kh[tt] = kh.v; Kl[tt] = kl.v;
    }
    s16x8 Vb[2][2];
#pragma unroll
    for (int mc = 0; mc < 2; ++mc)
#pragma unroll
        for (int dh = 0; dh < 2; ++dh) {
            FragU fu;
#pragma unroll
            for (int wd = 0; wd < 4; ++wd)
                fu.w[wd] = pk_bf16(va[mc][dh][2 * wd], va[mc][dh][2 * wd + 1]);
            Vb[mc][dh] = fu.v;
        }

    // ---- S^T = K·Q^T tile loop, fused exp2 + bf16 pack + denom ----
    const int cls = ((wr == 7) ? 2 : 0) | ((wc == 7) ? 1 : 0);
    const float* bmh = bm + (h * 4 + cls) * 4096;

    uint32_t u0[4][4], u1[4][4];
    float inv[4];
#pragma unroll
    for (int tq = 0; tq < 4; ++tq) {
        float dsum = 0.f;
#pragma unroll
        for (int tk = 0; tk < 4; ++tk) {
            f32x4 a = *(const f32x4*)(bmh + (16 * tq + l16) * 64 + 16 * tk + 4 * g);
            a = __builtin_amdgcn_mfma_f32_16x16x32_bf16(Kl[tk], Qh[tq], a, 0, 0, 0);
            a = __builtin_amdgcn_mfma_f32_16x16x32_bf16(Kh[tk], Qh[tq], a, 0, 0, 0);
            float e0 = __builtin_amdgcn_exp2f(a[0]);
            float e1 = __builtin_amdgcn_exp2f(a[1]);
            float e2 = __builtin_amdgcn_exp2f(a[2]);
            float e3 = __builtin_amdgcn_exp2f(a[3]);
            dsum += (e0 + e1) + (e2 + e3);
            u0[tq][tk] = pk_bf16(e0, e1);
            u1[tq][tk] = pk_bf16(e2, e3);
        }
        dsum += __shfl_xor(dsum, 16);
        dsum += __shfl_xor(dsum, 32);
        inv[tq] = 1.0f / (dsum + 1e-30f);
    }

    // ---- repack P (C-layout) -> A-fragments for PV ----
    // dest A-frag PA[tq][mc]: lane holds P[q=16tq+l16][m=32mc+8g+e]
    // word w (e=2w,2w+1): src lane = 32*(g&1) + 16*(w>>1) + l16,
    // src tile tk = 2mc + (g>>1) (select via lane>=32), src word = u_{w&1}
    const int srcb = 32 * (g & 1) + l16;
    const bool hiG = (lane >= 32);
    s16x8 PA[4][2];
#pragma unroll
    for (int tq = 0; tq < 4; ++tq)
#pragma unroll
        for (int mc = 0; mc < 2; ++mc) {
            FragU fu;
#pragma unroll
            for (int wd = 0; wd < 4; ++wd) {
                const int sl = srcb + 16 * (wd >> 1);
                uint32_t A, B;
                if (wd & 1) {
                    A = __shfl(u1[tq][2 * mc],     sl);
                    B = __shfl(u1[tq][2 * mc + 1], sl);
                } else {
                    A = __shfl(u0[tq][2 * mc],     sl);
                    B = __shfl(u0[tq][2 * mc + 1], sl);
                }
                fu.w[wd] = hiG ? B : A;
            }
            PA[tq][mc] = fu.v;
        }

    // ---- O = P·V, normalize + store ----
    // row q = 16tq + 4g + r, col d = 16dh + l16
#pragma unroll
    for (int tq = 0; tq < 4; ++tq) {
        f32x4 acc[2];
#pragma unroll
        for (int dh = 0; dh < 2; ++dh) {
            f32x4 a = {0.f, 0.f, 0.f, 0.f};
            a = __builtin_amdgcn_mfma_f32_16x16x32_bf16(PA[tq][0], Vb[0][dh], a, 0, 0, 0);
            a = __builtin_amdgcn_mfma_f32_16x16x32_bf16(PA[tq][1], Vb[1][dh], a, 0, 0, 0);
            acc[dh] = a;
        }
#pragma unroll
        for (int r = 0; r < 4; ++r) {
            const float iv = __shfl(inv[tq], 4 * g + r);
            const int oo = __shfl(off_t, 16 * tq + 4 * g + r);
            if (tq < 3 || (g == 0 && r == 0)) {
#pragma unroll
                for (int dh = 0; dh < 2; ++dh)
                    outg[oo + 16 * dh + l16] = acc[dh][r] * iv;
            }
        }
    }
}

// ---------------- fallback scalar kernel (round-3) ----------------
__global__ __launch_bounds__(256)
void swin_block_scalar(const float* __restrict__ qg,
                       const float* __restrict__ kg,
                       const float* __restrict__ vg,
                       const float* __restrict__ bias,
                       float* __restrict__ outg)
{
    const int wave = __builtin_amdgcn_readfirstlane(threadIdx.x >> 6);
    const int wh   = blockIdx.x * 4 + wave;
    const int h    = wh & (NH_ - 1);
    const int w    = wh >> 4;
    const int wc   = w & 7;
    const int wr   = (w >> 3) & 7;
    const int b    = w >> 6;

    const int lane = threadIdx.x & 63;
    const int rr   = lane < NTOK ? lane : NTOK - 1;
    const int i    = rr / WSZ;
    const int j    = rr - i * WSZ;

    const int hp = wr * WSZ + i;
    const int wp = wc * WSZ + j;
    int sr = hp + 3; if (sr >= SP) sr -= SP;
    int sc = wp + 3; if (sc >= SP) sc -= SP;
    const int rowoff = ((b * SP + sr) * SP + sc) * CH + h * HD_;
    const int reg_r = (hp < 49 ? 0 : (hp < 53 ? 3 : 6))
                    + (wp < 49 ? 0 : (wp < 53 ? 1 : 2));
    const float qscale = 0.17677669529663687f * LOG2E;

    float qr[HD_];
    {
        const float4* qp = reinterpret_cast<const float4*>(qg + rowoff);
#pragma unroll
        for (int tt = 0; tt < HD_ / 4; ++tt) {
            float4 x = qp[tt];
            qr[4*tt+0] = x.x * qscale; qr[4*tt+1] = x.y * qscale;
            qr[4*tt+2] = x.z * qscale; qr[4*tt+3] = x.w * qscale;
        }
    }
    const int biaslane = (i * 13 + j) * 16 + h;
    float o[HD_];
#pragma unroll
    for (int d = 0; d < HD_; ++d) o[d] = 0.f;
    float denom = 0.f;
    const float* kb = kg + b * SP * SP * CH + h * HD_;
    const float* vb = vg + b * SP * SP * CH + h * HD_;

    for (int ic = 0; ic < WSZ; ++ic) {
        const int hpc = wr * WSZ + ic;
        int src_r = hpc + 3; if (src_r >= SP) src_r -= SP;
        const int regh_c = (hpc < 49 ? 0 : (hpc < 53 ? 3 : 6));
        const float* krow0 = kb + src_r * SP * CH;
        const float* vrow0 = vb + src_r * SP * CH;
        float e[WSZ];
#pragma unroll
        for (int u = 0; u < WSZ; ++u) {
            const int wpc = wc * WSZ + u;
            int src_c = wpc + 3; if (src_c >= SP) src_c -= SP;
            const int reg_c = regh_c + (wpc < 49 ? 0 : (wpc < 53 ? 1 : 2));
            const float* krow = krow0 + src_c * CH;
            const float bv = bias[biaslane + ((6 - ic) * 13 + (6 - u)) * 16];
            float s0 = fmaf(bv, LOG2E, (reg_r != reg_c) ? -167.26950408889634f : -23.0f);
            float s1 = 0.f, s2 = 0.f, s3 = 0.f;
#pragma unroll
            for (int d = 0; d < HD_; d += 4) {
                s0 = fmaf(qr[d+0], krow[d+0], s0);
                s1 = fmaf(qr[d+1], krow[d+1], s1);
                s2 = fmaf(qr[d+2], krow[d+2], s2);
                s3 = fmaf(qr[d+3], krow[d+3], s3);
            }
            e[u] = exp2f((s0 + s1) + (s2 + s3));
            denom += e[u];
        }
#pragma unroll
        for (int u = 0; u < WSZ; ++u) {
            const int wpc = wc * WSZ + u;
            int src_c = wpc + 3; if (src_c >= SP) src_c -= SP;
            const float* vrow = vrow0 + src_c * CH;
            const float ev = e[u];
#pragma unroll
            for (int d = 0; d < HD_; ++d) o[d] = fmaf(ev, vrow[d], o[d]);
        }
    }
    const float invd = 1.0f / denom;
    if (lane < NTOK) {
        float4* op = reinterpret_cast<float4*>(outg + rowoff);
#pragma unroll
        for (int tt = 0; tt < HD_ / 4; ++tt) {
            float4 x;
            x.x = o[4*tt+0] * invd; x.y = o[4*tt+1] * invd;
            x.z = o[4*tt+2] * invd; x.w = o[4*tt+3] * invd;
            op[tt] = x;
        }
    }
}

extern "C" void kernel_launch(void* const* d_in, const int* in_sizes, int n_in,
                              void* d_out, int out_size, void* d_ws, size_t ws_size,
                              hipStream_t stream) {
    const float* q    = (const float*)d_in[0];
    const float* k    = (const float*)d_in[1];
    const float* v    = (const float*)d_in[2];
    const float* bias = (const float*)d_in[3];
    float* out        = (float*)d_out;

    const int B   = in_sizes[0] / (SP * SP * CH);
    const int nwh = B * (SP / WSZ) * (SP / WSZ) * NH_;   // 16384

    const size_t bm_bytes = (size_t)NH_ * 4 * 64 * 64 * sizeof(float);  // 1 MB
    if (ws_size >= bm_bytes) {
        float* bm = (float*)d_ws;
        hipLaunchKernelGGL(build_bm, dim3(NH_ * 4), dim3(256), 0, stream, bias, bm);
        hipLaunchKernelGGL(swin_mfma_kernel, dim3(nwh / 4), dim3(256), 0, stream,
                           q, k, v, bm, out);
    } else {
        hipLaunchKernelGGL(swin_block_scalar, dim3(nwh / 4), dim3(256), 0, stream,
                           q, k, v, bias, out);
    }
}

// Round 9
// 118.202 us; speedup vs baseline: 1.0226x; 1.0019x over previous
//
#include <hip/hip_runtime.h>
#include <stdint.h>

// Swin shifted-window attention, MI355X (gfx950) — MFMA version, round 9.
// ONE change vs round 8: XCD-aware blockIdx swizzle. The 4 blocks covering
// one window's 16 heads previously landed on 4 different XCDs (round-robin
// bid%8), so each 2KB pixel row (all 16 heads, contiguous) was fetched into
// 4 non-coherent L2s -> ~4x L2-fill traffic through L3. Now all 4 blocks of
// window w share bid%8 == w%8 -> one XCD, one L2 fill per line.
// bid = (w%8) + 8*((w/8)*4 + sub);  w = (bid%8) + 8*(bid>>5); sub=(bid>>3)&3.

constexpr int WSZ  = 7;
constexpr int NTOK = 49;
constexpr int NH_  = 16;
constexpr int HD_  = 32;
constexpr int SP   = 56;
constexpr int CH   = 512;
constexpr float LOG2E = 1.4426950408889634f;

typedef float  f32x4 __attribute__((ext_vector_type(4)));
typedef short  s16x8 __attribute__((ext_vector_type(8)));

union FragU { uint32_t w[4]; s16x8 v; };

// round-to-nearest-even bf16 of a float, as the TOP 16 bits (low 16 zero)
__device__ inline uint32_t bf16_hibits(float x) {
    uint32_t u = __float_as_uint(x);
    u += 0x7fffu + ((u >> 16) & 1u);
    return u & 0xffff0000u;
}

// pack two floats to bf16 pair (low half = a, high half = b)
__device__ inline uint32_t pk_bf16(float a, float b) {
    return (bf16_hibits(a) >> 16) | bf16_hibits(b);
}

// hi/lo bf16 split of a pair: wh = bf16(a,b); wl = bf16 of residuals
__device__ inline void hilo_pair(float a, float b, uint32_t& wh, uint32_t& wl) {
    uint32_t ah = bf16_hibits(a), bh = bf16_hibits(b);
    wh = (ah >> 16) | bh;
    float ra = a - __uint_as_float(ah);
    float rb = b - __uint_as_float(bh);
    wl = pk_bf16(ra, rb);
}

// ---------------- pre-kernel: bias+mask matrices ----------------
// bm[h][cls][q][m] (64x64 each), cls = (wr==7)*2 + (wc==7).
// value = LOG2E*(bias + mask) - 23 for valid q,m<49; -1e9 for padding.
__global__ __launch_bounds__(256)
void build_bm(const float* __restrict__ bias, float* __restrict__ bm)
{
    const int blk = blockIdx.x;          // h*4 + cls
    const int h = blk >> 2, cls = blk & 3;
    for (int idx = threadIdx.x; idx < 4096; idx += 256) {
        const int q = idx >> 6, m = idx & 63;
        float val;
        if (q >= NTOK || m >= NTOK) {
            val = -1e9f;
        } else {
            const int iq = q / 7, jq = q % 7, im = m / 7, jm = m % 7;
            const int rpi = (iq - im + 6) * 13 + (jq - jm + 6);
            const float bv = bias[rpi * NH_ + h];
            const int rq = ((cls & 2) ? (iq < 4 ? 3 : 6) : 0)
                         + ((cls & 1) ? (jq < 4 ? 1 : 2) : 0);
            const int rm = ((cls & 2) ? (im < 4 ? 3 : 6) : 0)
                         + ((cls & 1) ? (jm < 4 ? 1 : 2) : 0);
            const float mask = (rq != rm) ? -100.0f : 0.0f;
            val = (bv + mask) * LOG2E - 23.0f;
        }
        bm[blk * 4096 + idx] = val;
    }
}

// ---------------- main MFMA kernel ----------------
__global__ __launch_bounds__(256, 2)
void swin_mfma_kernel(const float* __restrict__ qg,
                      const float* __restrict__ kg,
                      const float* __restrict__ vg,
                      const float* __restrict__ bm,
                      float* __restrict__ outg)
{
    // XCD swizzle: all 4 sub-blocks of window w share bid%8 (same XCD L2).
    const int bid  = blockIdx.x;
    const int w    = (bid & 7) + 8 * (bid >> 5);   // window id 0..4095
    const int sub  = (bid >> 3) & 3;               // head-quad 0..3
    const int wave = threadIdx.x >> 6;
    const int h    = sub * 4 + wave;               // head 0..15
    const int wc   = w & 7;
    const int wr   = (w >> 3) & 7;
    const int b    = w >> 6;

    const int lane = threadIdx.x & 63;
    const int g    = lane >> 4;       // 16-lane group 0..3
    const int l16  = lane & 15;

    // per-lane token offset: token = lane (clamped to 48)
    const int t  = lane < NTOK ? lane : NTOK - 1;
    const int it = t / 7, jt = t - 7 * it;
    int sr = wr * 7 + it + 3; if (sr >= SP) sr -= SP;
    int sc = wc * 7 + jt + 3; if (sc >= SP) sc -= SP;
    const int off_t = ((b * SP + sr) * SP + sc) * CH + h * HD_;

    // ---- phase 1: ALL addresses (shuffles), then ALL raw loads ----
    int oQK[4];
#pragma unroll
    for (int tt = 0; tt < 4; ++tt)
        oQK[tt] = __shfl(off_t, 16 * tt + l16);
    int oV[16];
#pragma unroll
    for (int mc = 0; mc < 2; ++mc)
#pragma unroll
        for (int e = 0; e < 8; ++e)
            oV[8 * mc + e] = __shfl(off_t, 32 * mc + 8 * g + e);

    // Q,K: token = 16*tt + l16, d = 8g..8g+7  (16 x float4, independent)
    float4 qa[4][2], ka[4][2];
#pragma unroll
    for (int tt = 0; tt < 4; ++tt) {
        const float* qp = qg + oQK[tt] + 8 * g;
        const float* kp = kg + oQK[tt] + 8 * g;
        qa[tt][0] = *(const float4*)qp;
        qa[tt][1] = *(const float4*)(qp + 4);
        ka[tt][0] = *(const float4*)kp;
        ka[tt][1] = *(const float4*)(kp + 4);
    }
    // V: token m = 32mc + 8g + e, d = 16dh + l16  (32 scalar, independent)
    float va[2][2][8];
#pragma unroll
    for (int mc = 0; mc < 2; ++mc)
#pragma unroll
        for (int dh = 0; dh < 2; ++dh)
#pragma unroll
            for (int e = 0; e < 8; ++e)
                va[mc][dh][e] = vg[oV[8 * mc + e] + 16 * dh + l16];

    const float qs = 0.17677669529663687f * LOG2E;  // (1/sqrt(32))*log2(e)

    // ---- phase 2: converts ----
    // Q: single bf16 (pre-scaled). K: hi/lo split. V: single bf16.
    s16x8 Qh[4], Kh[4], Kl[4];
#pragma unroll
    for (int tt = 0; tt < 4; ++tt) {
        FragU qh, kh, kl;
        qh.w[0] = pk_bf16(qa[tt][0].x * qs, qa[tt][0].y * qs);
        qh.w[1] = pk_bf16(qa[tt][0].z * qs, qa[tt][0].w * qs);
        qh.w[2] = pk_bf16(qa[tt][1].x * qs, qa[tt][1].y * qs);
        qh.w[3] = pk_bf16(qa[tt][1].z * qs, qa[tt][1].w * qs);
        hilo_pair(ka[tt][0].x, ka[tt][0].y, kh.w[0], kl.w[0]);
        hilo_pair(ka[tt][0].z, ka[tt][0].w, kh.w[1], kl.w[1]);
        hilo_pair(ka[tt][1].x, ka[tt][1].y, kh.w[2], kl.w[2]);
        hilo_pair(ka[tt][1].z, ka[tt][1].w, kh.w[3], kl.w[3]);
        Qh[tt] = qh.v; Kh[tt] = kh.v; Kl[tt] = kl.v;
    }
    s16x8 Vb[2][2];
#pragma unroll
    for (int mc = 0; mc < 2; ++mc)
#pragma unroll
        for (int dh = 0; dh < 2; ++dh) {
            FragU fu;
#pragma unroll
            for (int wd = 0; wd < 4; ++wd)
                fu.w[wd] = pk_bf16(va[mc][dh][2 * wd], va[mc][dh][2 * wd + 1]);
            Vb[mc][dh] = fu.v;
        }

    // ---- S^T = K·Q^T tile loop, fused exp2 + bf16 pack + denom ----
    const int cls = ((wr == 7) ? 2 : 0) | ((wc == 7) ? 1 : 0);
    const float* bmh = bm + (h * 4 + cls) * 4096;

    uint32_t u0[4][4], u1[4][4];
    float inv[4];
#pragma unroll
    for (int tq = 0; tq < 4; ++tq) {
        float dsum = 0.f;
#pragma unroll
        for (int tk = 0; tk < 4; ++tk) {
            f32x4 a = *(const f32x4*)(bmh + (16 * tq + l16) * 64 + 16 * tk + 4 * g);
            a = __builtin_amdgcn_mfma_f32_16x16x32_bf16(Kl[tk], Qh[tq], a, 0, 0, 0);
            a = __builtin_amdgcn_mfma_f32_16x16x32_bf16(Kh[tk], Qh[tq], a, 0, 0, 0);
            float e0 = __builtin_amdgcn_exp2f(a[0]);
            float e1 = __builtin_amdgcn_exp2f(a[1]);
            float e2 = __builtin_amdgcn_exp2f(a[2]);
            float e3 = __builtin_amdgcn_exp2f(a[3]);
            dsum += (e0 + e1) + (e2 + e3);
            u0[tq][tk] = pk_bf16(e0, e1);
            u1[tq][tk] = pk_bf16(e2, e3);
        }
        dsum += __shfl_xor(dsum, 16);
        dsum += __shfl_xor(dsum, 32);
        inv[tq] = 1.0f / (dsum + 1e-30f);
    }

    // ---- repack P (C-layout) -> A-fragments for PV ----
    // dest A-frag PA[tq][mc]: lane holds P[q=16tq+l16][m=32mc+8g+e]
    // word w (e=2w,2w+1): src lane = 32*(g&1) + 16*(w>>1) + l16,
    // src tile tk = 2mc + (g>>1) (select via lane>=32), src word = u_{w&1}
    const int srcb = 32 * (g & 1) + l16;
    const bool hiG = (lane >= 32);
    s16x8 PA[4][2];
#pragma unroll
    for (int tq = 0; tq < 4; ++tq)
#pragma unroll
        for (int mc = 0; mc < 2; ++mc) {
            FragU fu;
#pragma unroll
            for (int wd = 0; wd < 4; ++wd) {
                const int sl = srcb + 16 * (wd >> 1);
                uint32_t A, B;
                if (wd & 1) {
                    A = __shfl(u1[tq][2 * mc],     sl);
                    B = __shfl(u1[tq][2 * mc + 1], sl);
                } else {
                    A = __shfl(u0[tq][2 * mc],     sl);
                    B = __shfl(u0[tq][2 * mc + 1], sl);
                }
                fu.w[wd] = hiG ? B : A;
            }
            PA[tq][mc] = fu.v;
        }

    // ---- O = P·V, normalize + store ----
    // row q = 16tq + 4g + r, col d = 16dh + l16
#pragma unroll
    for (int tq = 0; tq < 4; ++tq) {
        f32x4 acc[2];
#pragma unroll
        for (int dh = 0; dh < 2; ++dh) {
            f32x4 a = {0.f, 0.f, 0.f, 0.f};
            a = __builtin_amdgcn_mfma_f32_16x16x32_bf16(PA[tq][0], Vb[0][dh], a, 0, 0, 0);
            a = __builtin_amdgcn_mfma_f32_16x16x32_bf16(PA[tq][1], Vb[1][dh], a, 0, 0, 0);
            acc[dh] = a;
        }
#pragma unroll
        for (int r = 0; r < 4; ++r) {
            const float iv = __shfl(inv[tq], 4 * g + r);
            const int oo = __shfl(off_t, 16 * tq + 4 * g + r);
            if (tq < 3 || (g == 0 && r == 0)) {
#pragma unroll
                for (int dh = 0; dh < 2; ++dh)
                    outg[oo + 16 * dh + l16] = acc[dh][r] * iv;
            }
        }
    }
}

// ---------------- fallback scalar kernel (round-3) ----------------
__global__ __launch_bounds__(256)
void swin_block_scalar(const float* __restrict__ qg,
                       const float* __restrict__ kg,
                       const float* __restrict__ vg,
                       const float* __restrict__ bias,
                       float* __restrict__ outg)
{
    const int wave = __builtin_amdgcn_readfirstlane(threadIdx.x >> 6);
    const int wh   = blockIdx.x * 4 + wave;
    const int h    = wh & (NH_ - 1);
    const int w    = wh >> 4;
    const int wc   = w & 7;
    const int wr   = (w >> 3) & 7;
    const int b    = w >> 6;

    const int lane = threadIdx.x & 63;
    const int rr   = lane < NTOK ? lane : NTOK - 1;
    const int i    = rr / WSZ;
    const int j    = rr - i * WSZ;

    const int hp = wr * WSZ + i;
    const int wp = wc * WSZ + j;
    int sr = hp + 3; if (sr >= SP) sr -= SP;
    int sc = wp + 3; if (sc >= SP) sc -= SP;
    const int rowoff = ((b * SP + sr) * SP + sc) * CH + h * HD_;
    const int reg_r = (hp < 49 ? 0 : (hp < 53 ? 3 : 6))
                    + (wp < 49 ? 0 : (wp < 53 ? 1 : 2));
    const float qscale = 0.17677669529663687f * LOG2E;

    float qr[HD_];
    {
        const float4* qp = reinterpret_cast<const float4*>(qg + rowoff);
#pragma unroll
        for (int tt = 0; tt < HD_ / 4; ++tt) {
            float4 x = qp[tt];
            qr[4*tt+0] = x.x * qscale; qr[4*tt+1] = x.y * qscale;
            qr[4*tt+2] = x.z * qscale; qr[4*tt+3] = x.w * qscale;
        }
    }
    const int biaslane = (i * 13 + j) * 16 + h;
    float o[HD_];
#pragma unroll
    for (int d = 0; d < HD_; ++d) o[d] = 0.f;
    float denom = 0.f;
    const float* kb = kg + b * SP * SP * CH + h * HD_;
    const float* vb = vg + b * SP * SP * CH + h * HD_;

    for (int ic = 0; ic < WSZ; ++ic) {
        const int hpc = wr * WSZ + ic;
        int src_r = hpc + 3; if (src_r >= SP) src_r -= SP;
        const int regh_c = (hpc < 49 ? 0 : (hpc < 53 ? 3 : 6));
        const float* krow0 = kb + src_r * SP * CH;
        const float* vrow0 = vb + src_r * SP * CH;
        float e[WSZ];
#pragma unroll
        for (int u = 0; u < WSZ; ++u) {
            const int wpc = wc * WSZ + u;
            int src_c = wpc + 3; if (src_c >= SP) src_c -= SP;
            const int reg_c = regh_c + (wpc < 49 ? 0 : (wpc < 53 ? 1 : 2));
            const float* krow = krow0 + src_c * CH;
            const float bv = bias[biaslane + ((6 - ic) * 13 + (6 - u)) * 16];
            float s0 = fmaf(bv, LOG2E, (reg_r != reg_c) ? -167.26950408889634f : -23.0f);
            float s1 = 0.f, s2 = 0.f, s3 = 0.f;
#pragma unroll
            for (int d = 0; d < HD_; d += 4) {
                s0 = fmaf(qr[d+0], krow[d+0], s0);
                s1 = fmaf(qr[d+1], krow[d+1], s1);
                s2 = fmaf(qr[d+2], krow[d+2], s2);
                s3 = fmaf(qr[d+3], krow[d+3], s3);
            }
            e[u] = exp2f((s0 + s1) + (s2 + s3));
            denom += e[u];
        }
#pragma unroll
        for (int u = 0; u < WSZ; ++u) {
            const int wpc = wc * WSZ + u;
            int src_c = wpc + 3; if (src_c >= SP) src_c -= SP;
            const float* vrow = vrow0 + src_c * CH;
            const float ev = e[u];
#pragma unroll
            for (int d = 0; d < HD_; ++d) o[d] = fmaf(ev, vrow[d], o[d]);
        }
    }
    const float invd = 1.0f / denom;
    if (lane < NTOK) {
        float4* op = reinterpret_cast<float4*>(outg + rowoff);
#pragma unroll
        for (int tt = 0; tt < HD_ / 4; ++tt) {
            float4 x;
            x.x = o[4*tt+0] * invd; x.y = o[4*tt+1] * invd;
            x.z = o[4*tt+2] * invd; x.w = o[4*tt+3] * invd;
            op[tt] = x;
        }
    }
}

extern "C" void kernel_launch(void* const* d_in, const int* in_sizes, int n_in,
                              void* d_out, int out_size, void* d_ws, size_t ws_size,
                              hipStream_t stream) {
    const float* q    = (const float*)d_in[0];
    const float* k    = (const float*)d_in[1];
    const float* v    = (const float*)d_in[2];
    const float* bias = (const float*)d_in[3];
    float* out        = (float*)d_out;

    const int B   = in_sizes[0] / (SP * SP * CH);
    const int nwh = B * (SP / WSZ) * (SP / WSZ) * NH_;   // 16384

    const size_t bm_bytes = (size_t)NH_ * 4 * 64 * 64 * sizeof(float);  // 1 MB
    if (ws_size >= bm_bytes) {
        float* bm = (float*)d_ws;
        hipLaunchKernelGGL(build_bm, dim3(NH_ * 4), dim3(256), 0, stream, bias, bm);
        hipLaunchKernelGGL(swin_mfma_kernel, dim3(nwh / 4), dim3(256), 0, stream,
                           q, k, v, bm, out);
    } else {
        hipLaunchKernelGGL(swin_block_scalar, dim3(nwh / 4), dim3(256), 0, stream,
                           q, k, v, bias, out);
    }
}

// Round 10
// 113.070 us; speedup vs baseline: 1.0690x; 1.0454x over previous
//
#include <hip/hip_runtime.h>
#include <stdint.h>

// Swin shifted-window attention, MI355X (gfx950) — MFMA version, round 10.
// ONE mechanism change vs r9: force per-wave memory-level parallelism with
// __builtin_amdgcn_sched_barrier(0). Evidence: per-wave time ~60k cycles ≈
// 48 VMEM loads serialized at ~900cy HBM latency (Little's law: only ~1.7
// lines in flight per wave), and VGPR_Count=60 proves the scheduler re-rolls
// the r8 flat-load block into load->convert chains. The sched_barrier pins
// ALL Q/K/V loads + all 16 bm C-init fragments BEFORE any consumer, so ~64
// VMEM ops issue back-to-back (VGPR should jump to ~160-220 — that's the
// observable). One wave per (window,head); no LDS, no barriers.

constexpr int WSZ  = 7;
constexpr int NTOK = 49;
constexpr int NH_  = 16;
constexpr int HD_  = 32;
constexpr int SP   = 56;
constexpr int CH   = 512;
constexpr float LOG2E = 1.4426950408889634f;

typedef float  f32x4 __attribute__((ext_vector_type(4)));
typedef short  s16x8 __attribute__((ext_vector_type(8)));

union FragU { uint32_t w[4]; s16x8 v; };

// round-to-nearest-even bf16 of a float, as the TOP 16 bits (low 16 zero)
__device__ inline uint32_t bf16_hibits(float x) {
    uint32_t u = __float_as_uint(x);
    u += 0x7fffu + ((u >> 16) & 1u);
    return u & 0xffff0000u;
}

// pack two floats to bf16 pair (low half = a, high half = b)
__device__ inline uint32_t pk_bf16(float a, float b) {
    return (bf16_hibits(a) >> 16) | bf16_hibits(b);
}

// hi/lo bf16 split of a pair: wh = bf16(a,b); wl = bf16 of residuals
__device__ inline void hilo_pair(float a, float b, uint32_t& wh, uint32_t& wl) {
    uint32_t ah = bf16_hibits(a), bh = bf16_hibits(b);
    wh = (ah >> 16) | bh;
    float ra = a - __uint_as_float(ah);
    float rb = b - __uint_as_float(bh);
    wl = pk_bf16(ra, rb);
}

// ---------------- pre-kernel: bias+mask matrices ----------------
// bm[h][cls][q][m] (64x64 each), cls = (wr==7)*2 + (wc==7).
// value = LOG2E*(bias + mask) - 23 for valid q,m<49; -1e9 for padding.
__global__ __launch_bounds__(256)
void build_bm(const float* __restrict__ bias, float* __restrict__ bm)
{
    const int blk = blockIdx.x;          // h*4 + cls
    const int h = blk >> 2, cls = blk & 3;
    for (int idx = threadIdx.x; idx < 4096; idx += 256) {
        const int q = idx >> 6, m = idx & 63;
        float val;
        if (q >= NTOK || m >= NTOK) {
            val = -1e9f;
        } else {
            const int iq = q / 7, jq = q % 7, im = m / 7, jm = m % 7;
            const int rpi = (iq - im + 6) * 13 + (jq - jm + 6);
            const float bv = bias[rpi * NH_ + h];
            const int rq = ((cls & 2) ? (iq < 4 ? 3 : 6) : 0)
                         + ((cls & 1) ? (jq < 4 ? 1 : 2) : 0);
            const int rm = ((cls & 2) ? (im < 4 ? 3 : 6) : 0)
                         + ((cls & 1) ? (jm < 4 ? 1 : 2) : 0);
            const float mask = (rq != rm) ? -100.0f : 0.0f;
            val = (bv + mask) * LOG2E - 23.0f;
        }
        bm[blk * 4096 + idx] = val;
    }
}

// ---------------- main MFMA kernel ----------------
__global__ __launch_bounds__(256, 2)
void swin_mfma_kernel(const float* __restrict__ qg,
                      const float* __restrict__ kg,
                      const float* __restrict__ vg,
                      const float* __restrict__ bm,
                      float* __restrict__ outg)
{
    // XCD swizzle (r9): all 4 sub-blocks of window w share bid%8.
    const int bid  = blockIdx.x;
    const int w    = (bid & 7) + 8 * (bid >> 5);   // window id 0..4095
    const int sub  = (bid >> 3) & 3;               // head-quad 0..3
    const int wave = threadIdx.x >> 6;
    const int h    = sub * 4 + wave;               // head 0..15
    const int wc   = w & 7;
    const int wr   = (w >> 3) & 7;
    const int b    = w >> 6;

    const int lane = threadIdx.x & 63;
    const int g    = lane >> 4;       // 16-lane group 0..3
    const int l16  = lane & 15;

    // per-lane token offset: token = lane (clamped to 48)
    const int t  = lane < NTOK ? lane : NTOK - 1;
    const int it = t / 7, jt = t - 7 * it;
    int sr = wr * 7 + it + 3; if (sr >= SP) sr -= SP;
    int sc = wc * 7 + jt + 3; if (sc >= SP) sc -= SP;
    const int off_t = ((b * SP + sr) * SP + sc) * CH + h * HD_;

    // ---- all addresses ----
    int oQK[4];
#pragma unroll
    for (int tt = 0; tt < 4; ++tt)
        oQK[tt] = __shfl(off_t, 16 * tt + l16);
    int oV[16];
#pragma unroll
    for (int mc = 0; mc < 2; ++mc)
#pragma unroll
        for (int e = 0; e < 8; ++e)
            oV[8 * mc + e] = __shfl(off_t, 32 * mc + 8 * g + e);

    const int cls = ((wr == 7) ? 2 : 0) | ((wc == 7) ? 1 : 0);
    const float* bmh = bm + (h * 4 + cls) * 4096;

    // ---- issue ALL loads back-to-back (48 VMEM + 16 bm VMEM) ----
    // Q,K: token = 16*tt + l16, d = 8g..8g+7  (16 x dwordx4)
    float4 qa[4][2], ka[4][2];
#pragma unroll
    for (int tt = 0; tt < 4; ++tt) {
        const float* qp = qg + oQK[tt] + 8 * g;
        const float* kp = kg + oQK[tt] + 8 * g;
        qa[tt][0] = *(const float4*)qp;
        qa[tt][1] = *(const float4*)(qp + 4);
        ka[tt][0] = *(const float4*)kp;
        ka[tt][1] = *(const float4*)(kp + 4);
    }
    // V: token m = 32mc + 8g + e, d = 16dh + l16  (32 x dword)
    float va[2][2][8];
#pragma unroll
    for (int mc = 0; mc < 2; ++mc)
#pragma unroll
        for (int dh = 0; dh < 2; ++dh)
#pragma unroll
            for (int e = 0; e < 8; ++e)
                va[mc][dh][e] = vg[oV[8 * mc + e] + 16 * dh + l16];
    // bm C-init fragments (16 x dwordx4, L2-hot): prefetched so the S-loop
    // has zero memory waits.
    f32x4 bmf[4][4];
#pragma unroll
    for (int tq = 0; tq < 4; ++tq)
#pragma unroll
        for (int tk = 0; tk < 4; ++tk)
            bmf[tq][tk] = *(const f32x4*)(bmh + (16 * tq + l16) * 64 + 16 * tk + 4 * g);

    // HARD scheduling fence: nothing below may move above; the scheduler
    // cannot sink the loads into their consumers (which is what erased the
    // r8 flat-load restructure and kept only ~2 loads in flight).
    __builtin_amdgcn_sched_barrier(0);

    const float qs = 0.17677669529663687f * LOG2E;  // (1/sqrt(32))*log2(e)

    // ---- converts ----
    // Q: single bf16 (pre-scaled). K: hi/lo split. V: single bf16.
    s16x8 Qh[4], Kh[4], Kl[4];
#pragma unroll
    for (int tt = 0; tt < 4; ++tt) {
        FragU qh, kh, kl;
        qh.w[0] = pk_bf16(qa[tt][0].x * qs, qa[tt][0].y * qs);
        qh.w[1] = pk_bf16(qa[tt][0].z * qs, qa[tt][0].w * qs);
        qh.w[2] = pk_bf16(qa[tt][1].x * qs, qa[tt][1].y * qs);
        qh.w[3] = pk_bf16(qa[tt][1].z * qs, qa[tt][1].w * qs);
        hilo_pair(ka[tt][0].x, ka[tt][0].y, kh.w[0], kl.w[0]);
        hilo_pair(ka[tt][0].z, ka[tt][0].w, kh.w[1], kl.w[1]);
        hilo_pair(ka[tt][1].x, ka[tt][1].y, kh.w[2], kl.w[2]);
        hilo_pair(ka[tt][1].z, ka[tt][1].w, kh.w[3], kl.w[3]);
        Qh[tt] = qh.v; Kh[tt] = kh.v; Kl[tt] = kl.v;
    }
    s16x8 Vb[2][2];
#pragma unroll
    for (int mc = 0; mc < 2; ++mc)
#pragma unroll
        for (int dh = 0; dh < 2; ++dh) {
            FragU fu;
#pragma unroll
            for (int wd = 0; wd < 4; ++wd)
                fu.w[wd] = pk_bf16(va[mc][dh][2 * wd], va[mc][dh][2 * wd + 1]);
            Vb[mc][dh] = fu.v;
        }

    // ---- S^T = K·Q^T tile loop, fused exp2 + bf16 pack + denom ----
    uint32_t u0[4][4], u1[4][4];
    float inv[4];
#pragma unroll
    for (int tq = 0; tq < 4; ++tq) {
        float dsum = 0.f;
#pragma unroll
        for (int tk = 0; tk < 4; ++tk) {
            f32x4 a = bmf[tq][tk];
            a = __builtin_amdgcn_mfma_f32_16x16x32_bf16(Kl[tk], Qh[tq], a, 0, 0, 0);
            a = __builtin_amdgcn_mfma_f32_16x16x32_bf16(Kh[tk], Qh[tq], a, 0, 0, 0);
            float e0 = __builtin_amdgcn_exp2f(a[0]);
            float e1 = __builtin_amdgcn_exp2f(a[1]);
            float e2 = __builtin_amdgcn_exp2f(a[2]);
            float e3 = __builtin_amdgcn_exp2f(a[3]);
            dsum += (e0 + e1) + (e2 + e3);
            u0[tq][tk] = pk_bf16(e0, e1);
            u1[tq][tk] = pk_bf16(e2, e3);
        }
        dsum += __shfl_xor(dsum, 16);
        dsum += __shfl_xor(dsum, 32);
        inv[tq] = 1.0f / (dsum + 1e-30f);
    }

    // ---- repack P (C-layout) -> A-fragments for PV ----
    // dest A-frag PA[tq][mc]: lane holds P[q=16tq+l16][m=32mc+8g+e]
    // word w (e=2w,2w+1): src lane = 32*(g&1) + 16*(w>>1) + l16,
    // src tile tk = 2mc + (g>>1) (select via lane>=32), src word = u_{w&1}
    const int srcb = 32 * (g & 1) + l16;
    const bool hiG = (lane >= 32);
    s16x8 PA[4][2];
#pragma unroll
    for (int tq = 0; tq < 4; ++tq)
#pragma unroll
        for (int mc = 0; mc < 2; ++mc) {
            FragU fu;
#pragma unroll
            for (int wd = 0; wd < 4; ++wd) {
                const int sl = srcb + 16 * (wd >> 1);
                uint32_t A, B;
                if (wd & 1) {
                    A = __shfl(u1[tq][2 * mc],     sl);
                    B = __shfl(u1[tq][2 * mc + 1], sl);
                } else {
                    A = __shfl(u0[tq][2 * mc],     sl);
                    B = __shfl(u0[tq][2 * mc + 1], sl);
                }
                fu.w[wd] = hiG ? B : A;
            }
            PA[tq][mc] = fu.v;
        }

    // ---- O = P·V, normalize + store ----
    // row q = 16tq + 4g + r, col d = 16dh + l16
#pragma unroll
    for (int tq = 0; tq < 4; ++tq) {
        f32x4 acc[2];
#pragma unroll
        for (int dh = 0; dh < 2; ++dh) {
            f32x4 a = {0.f, 0.f, 0.f, 0.f};
            a = __builtin_amdgcn_mfma_f32_16x16x32_bf16(PA[tq][0], Vb[0][dh], a, 0, 0, 0);
            a = __builtin_amdgcn_mfma_f32_16x16x32_bf16(PA[tq][1], Vb[1][dh], a, 0, 0, 0);
            acc[dh] = a;
        }
#pragma unroll
        for (int r = 0; r < 4; ++r) {
            const float iv = __shfl(inv[tq], 4 * g + r);
            const int oo = __shfl(off_t, 16 * tq + 4 * g + r);
            if (tq < 3 || (g == 0 && r == 0)) {
#pragma unroll
                for (int dh = 0; dh < 2; ++dh)
                    outg[oo + 16 * dh + l16] = acc[dh][r] * iv;
            }
        }
    }
}

// ---------------- fallback scalar kernel (round-3) ----------------
__global__ __launch_bounds__(256)
void swin_block_scalar(const float* __restrict__ qg,
                       const float* __restrict__ kg,
                       const float* __restrict__ vg,
                       const float* __restrict__ bias,
                       float* __restrict__ outg)
{
    const int wave = __builtin_amdgcn_readfirstlane(threadIdx.x >> 6);
    const int wh   = blockIdx.x * 4 + wave;
    const int h    = wh & (NH_ - 1);
    const int w    = wh >> 4;
    const int wc   = w & 7;
    const int wr   = (w >> 3) & 7;
    const int b    = w >> 6;

    const int lane = threadIdx.x & 63;
    const int rr   = lane < NTOK ? lane : NTOK - 1;
    const int i    = rr / WSZ;
    const int j    = rr - i * WSZ;

    const int hp = wr * WSZ + i;
    const int wp = wc * WSZ + j;
    int sr = hp + 3; if (sr >= SP) sr -= SP;
    int sc = wp + 3; if (sc >= SP) sc -= SP;
    const int rowoff = ((b * SP + sr) * SP + sc) * CH + h * HD_;
    const int reg_r = (hp < 49 ? 0 : (hp < 53 ? 3 : 6))
                    + (wp < 49 ? 0 : (wp < 53 ? 1 : 2));
    const float qscale = 0.17677669529663687f * LOG2E;

    float qr[HD_];
    {
        const float4* qp = reinterpret_cast<const float4*>(qg + rowoff);
#pragma unroll
        for (int tt = 0; tt < HD_ / 4; ++tt) {
            float4 x = qp[tt];
            qr[4*tt+0] = x.x * qscale; qr[4*tt+1] = x.y * qscale;
            qr[4*tt+2] = x.z * qscale; qr[4*tt+3] = x.w * qscale;
        }
    }
    const int biaslane = (i * 13 + j) * 16 + h;
    float o[HD_];
#pragma unroll
    for (int d = 0; d < HD_; ++d) o[d] = 0.f;
    float denom = 0.f;
    const float* kb = kg + b * SP * SP * CH + h * HD_;
    const float* vb = vg + b * SP * SP * CH + h * HD_;

    for (int ic = 0; ic < WSZ; ++ic) {
        const int hpc = wr * WSZ + ic;
        int src_r = hpc + 3; if (src_r >= SP) src_r -= SP;
        const int regh_c = (hpc < 49 ? 0 : (hpc < 53 ? 3 : 6));
        const float* krow0 = kb + src_r * SP * CH;
        const float* vrow0 = vb + src_r * SP * CH;
        float e[WSZ];
#pragma unroll
        for (int u = 0; u < WSZ; ++u) {
            const int wpc = wc * WSZ + u;
            int src_c = wpc + 3; if (src_c >= SP) src_c -= SP;
            const int reg_c = regh_c + (wpc < 49 ? 0 : (wpc < 53 ? 1 : 2));
            const float* krow = krow0 + src_c * CH;
            const float bv = bias[biaslane + ((6 - ic) * 13 + (6 - u)) * 16];
            float s0 = fmaf(bv, LOG2E, (reg_r != reg_c) ? -167.26950408889634f : -23.0f);
            float s1 = 0.f, s2 = 0.f, s3 = 0.f;
#pragma unroll
            for (int d = 0; d < HD_; d += 4) {
                s0 = fmaf(qr[d+0], krow[d+0], s0);
                s1 = fmaf(qr[d+1], krow[d+1], s1);
                s2 = fmaf(qr[d+2], krow[d+2], s2);
                s3 = fmaf(qr[d+3], krow[d+3], s3);
            }
            e[u] = exp2f((s0 + s1) + (s2 + s3));
            denom += e[u];
        }
#pragma unroll
        for (int u = 0; u < WSZ; ++u) {
            const int wpc = wc * WSZ + u;
            int src_c = wpc + 3; if (src_c >= SP) src_c -= SP;
            const float* vrow = vrow0 + src_c * CH;
            const float ev = e[u];
#pragma unroll
            for (int d = 0; d < HD_; ++d) o[d] = fmaf(ev, vrow[d], o[d]);
        }
    }
    const float invd = 1.0f / denom;
    if (lane < NTOK) {
        float4* op = reinterpret_cast<float4*>(outg + rowoff);
#pragma unroll
        for (int tt = 0; tt < HD_ / 4; ++tt) {
            float4 x;
            x.x = o[4*tt+0] * invd; x.y = o[4*tt+1] * invd;
            x.z = o[4*tt+2] * invd; x.w = o[4*tt+3] * invd;
            op[tt] = x;
        }
    }
}

extern "C" void kernel_launch(void* const* d_in, const int* in_sizes, int n_in,
                              void* d_out, int out_size, void* d_ws, size_t ws_size,
                              hipStream_t stream) {
    const float* q    = (const float*)d_in[0];
    const float* k    = (const float*)d_in[1];
    const float* v    = (const float*)d_in[2];
    const float* bias = (const float*)d_in[3];
    float* out        = (float*)d_out;

    const int B   = in_sizes[0] / (SP * SP * CH);
    const int nwh = B * (SP / WSZ) * (SP / WSZ) * NH_;   // 16384

    const size_t bm_bytes = (size_t)NH_ * 4 * 64 * 64 * sizeof(float);  // 1 MB
    if (ws_size >= bm_bytes) {
        float* bm = (float*)d_ws;
        hipLaunchKernelGGL(build_bm, dim3(NH_ * 4), dim3(256), 0, stream, bias, bm);
        hipLaunchKernelGGL(swin_mfma_kernel, dim3(nwh / 4), dim3(256), 0, stream,
                           q, k, v, bm, out);
    } else {
        hipLaunchKernelGGL(swin_block_scalar, dim3(nwh / 4), dim3(256), 0, stream,
                           q, k, v, bias, out);
    }
}